// Round 12
// baseline (266.360 us; speedup 1.0000x reference)
//
#include <hip/hip_runtime.h>
#include <cstdint>

#define B_DIM 32
#define C_DIM 512
#define N_SP 1024
#define GROUPS 32
#define CPG 16
#define EPS 1e-5f

typedef __attribute__((ext_vector_type(8))) __bf16 bf16x8;
typedef __attribute__((ext_vector_type(4))) __bf16 bf16x4;
typedef __attribute__((ext_vector_type(4))) float f32x4;

__device__ __forceinline__ void gload16(const void* g, void* l) {
    __builtin_amdgcn_global_load_lds(
        (__attribute__((address_space(1))) void*)(unsigned long long)(uintptr_t)g,
        (__attribute__((address_space(3))) void*)(unsigned int)(uintptr_t)l,
        16, 0, 0);
}

// ------- fused GroupNorm: stats + apply + transpose, one x read -------
__global__ __launch_bounds__(256) void gn_fused_kernel(const float* __restrict__ x,
                                                       const float* __restrict__ w,
                                                       const float* __restrict__ bia,
                                                       __bf16* __restrict__ hT) {
    __shared__ float tile[16][1025];
    __shared__ float sw[16], sb[16];
    __shared__ float ls[4], lq[4];
    const int bb = blockIdx.x >> 5, g = blockIdx.x & 31;
    const int t = threadIdx.x;
    const float* xb = x + ((size_t)(bb * C_DIM + g * CPG)) * N_SP;

    float s = 0.f, sq = 0.f;
#pragma unroll
    for (int i = 0; i < 16; ++i) {
        int idx = t + 256 * i;
        int row = idx >> 8, c4 = (idx & 255) * 4;
        float4 v = *(const float4*)&xb[(size_t)row * N_SP + c4];
        tile[row][c4 + 0] = v.x; tile[row][c4 + 1] = v.y;
        tile[row][c4 + 2] = v.z; tile[row][c4 + 3] = v.w;
        s  += v.x + v.y + v.z + v.w;
        sq += v.x * v.x + v.y * v.y + v.z * v.z + v.w * v.w;
    }
    for (int off = 32; off > 0; off >>= 1) {
        s  += __shfl_xor(s, off);
        sq += __shfl_xor(sq, off);
    }
    int wid = t >> 6;
    if ((t & 63) == 0) { ls[wid] = s; lq[wid] = sq; }
    __syncthreads();
    if (t < 16) {
        s  = ls[0] + ls[1] + ls[2] + ls[3];
        sq = lq[0] + lq[1] + lq[2] + lq[3];
        float mean = s / (float)(CPG * N_SP);
        float var  = sq / (float)(CPG * N_SP) - mean * mean;
        float rstd = rsqrtf(var + EPS);
        float scl = w[g * CPG + t] * rstd;
        sw[t] = scl;
        sb[t] = bia[g * CPG + t] - mean * scl;
    }
    __syncthreads();
    __bf16* hb = hT + ((size_t)bb * N_SP) * C_DIM + g * CPG;
#pragma unroll
    for (int i = 0; i < 4; ++i) {
        int n = t + 256 * i;
        bf16x8 o1, o2;
#pragma unroll
        for (int c = 0; c < 8; ++c) o1[c] = (__bf16)(tile[c][n] * sw[c] + sb[c]);
#pragma unroll
        for (int c = 0; c < 8; ++c) o2[c] = (__bf16)(tile[8 + c][n] * sw[8 + c] + sb[8 + c]);
        *(bf16x8*)&hb[(size_t)n * C_DIM] = o1;
        *(bf16x8*)&hb[(size_t)n * C_DIM + 8] = o2;
    }
}

// ------- prep: weights fp32->bf16 + pack qk bias -------
__global__ __launch_bounds__(256) void prep_kernel(const float* __restrict__ qw,
                                                   const float* __restrict__ kw,
                                                   const float* __restrict__ vw,
                                                   const float* __restrict__ pw,
                                                   const float* __restrict__ qb,
                                                   const float* __restrict__ kb,
                                                   __bf16* __restrict__ wqk,
                                                   __bf16* __restrict__ wv,
                                                   __bf16* __restrict__ wp,
                                                   float* __restrict__ qkb) {
    int bi = blockIdx.x;
    int t = threadIdx.x;
    if (bi == 1024) {
        int i = t * 4;
#pragma unroll
        for (int e = 0; e < 4; ++e)
            qkb[i + e] = (i + e < 512) ? qb[i + e] : kb[i + e - 512];
        return;
    }
    const float* src;
    __bf16* dst;
    int blk = bi & 255;
    if (bi < 256)       { src = qw; dst = wqk; }
    else if (bi < 512)  { src = kw; dst = wqk + 262144; }
    else if (bi < 768)  { src = vw; dst = wv; }
    else                { src = pw; dst = wp; }
    int i = blk * 256 + t;
    float4 v = ((const float4*)src)[i];
    bf16x4 o;
    o[0] = (__bf16)v.x; o[1] = (__bf16)v.y; o[2] = (__bf16)v.z; o[3] = (__bf16)v.w;
    ((bf16x4*)dst)[i] = o;
}

// ------- fold 8 per-tile rowsum partials -> reciprocal -------
__global__ __launch_bounds__(256) void rs_fold(const float* __restrict__ RSp,
                                               float* __restrict__ RS) {
    int idx = blockIdx.x * 256 + threadIdx.x;   // b*1024 + row
    const float* p = RSp + (size_t)idx * 8;
    float s = ((p[0] + p[1]) + (p[2] + p[3])) + ((p[4] + p[5]) + (p[6] + p[7]));
    RS[idx] = 1.0f / s;
}

// ============ 128x128 8-wave GEMM, BK=64, dbuf, depth-1.5 prefetch ============
// EPI: 2 bf16+bias[row]; 4 f32+bias[row]+resid (resid prefetched in tail tile);
//      6 bf16+bias[col] split q/k (Y2 = kT);
//      7 scores: write bf16 exp(min(acc*scale,50)) + per-block rowsum partials
//        into Y2 = RS_p[b][row][8] (slot = bn/128), shfl+LDS reduce, NO atomics;
//      9 AV: bf16 acc * RSrecip[row] (RSrecip passed via resid, sR=1024)
#define WAITV(n) asm volatile("s_waitcnt vmcnt(" #n ")" ::: "memory")
#define BAR() __builtin_amdgcn_s_barrier()

template <int M, int N, int K, int LDA, int LDB, int EPI>
__global__ __launch_bounds__(512, 4) void gemmP(const __bf16* __restrict__ A, size_t sA,
                                                const __bf16* __restrict__ BT, size_t sB,
                                                void* __restrict__ Y, size_t sY,
                                                const float* __restrict__ bias,
                                                const float* __restrict__ resid, size_t sR,
                                                float scale, void* __restrict__ Y2) {
    static_assert(M % 128 == 0 && N % 128 == 0 && K % 128 == 0, "shape");
    constexpr int GX = N / 128, GY = M / 128, NT = K / 64;
    __shared__ __align__(16) __bf16 lds[2][2][8192];   // [buf][A/B][128 rows x 64 k]

    const int tid = threadIdx.x;
    const int w = tid >> 6, lane = tid & 63;
    const int wm = w >> 1, wn = w & 1;                 // 4 x 2 wave grid, tile 32x64
    const int lrow = lane & 15, koct = lane >> 4;

    const int nwg = gridDim.x;
    const int wg = ((int)blockIdx.x & 7) * (nwg >> 3) + ((int)blockIdx.x >> 3);
    const int bz = wg / (GX * GY);
    const int rem = wg - bz * (GX * GY);
    const int bm = (rem / GX) * 128, bn = (rem % GX) * 128;

    const __bf16* Ab = A + (size_t)bz * sA;
    const __bf16* Bb = BT + (size_t)bz * sB;

    const int srow = tid >> 3;
    const int kswz = ((tid & 7) ^ (srow & 7)) * 8;
    const __bf16* srcA = Ab + (size_t)(bm + srow) * LDA + kswz;
    const __bf16* srcB = Bb + (size_t)(bn + srow) * LDB + kswz;

#define STG(buf, kt) do { \
    gload16(srcA + (size_t)(kt) * 64,                      &lds[buf][0][w * 512]); \
    gload16(srcA + (size_t)64 * LDA + (size_t)(kt) * 64,   &lds[buf][0][4096 + w * 512]); \
    gload16(srcB + (size_t)(kt) * 64,                      &lds[buf][1][w * 512]); \
    gload16(srcB + (size_t)64 * LDB + (size_t)(kt) * 64,   &lds[buf][1][4096 + w * 512]); \
} while (0)

    const int ks0 = (koct ^ (lrow & 7)) * 8;
    const int ks1 = ks0 ^ 32;
    const int aoff = (wm * 32 + lrow) * 64;
    const int boff = (wn * 64 + lrow) * 64;

    bf16x8 aF[2][2], bF[4][2];
    f32x4 acc[2][4];
#pragma unroll
    for (int i = 0; i < 2; ++i)
#pragma unroll
        for (int j = 0; j < 4; ++j) acc[i][j] = (f32x4){0.f, 0.f, 0.f, 0.f};

    const float* Rb = (EPI == 4) ? (resid + (size_t)bz * sR) : nullptr;
    float xr[2][4][4];   // EPI==4 residual prefetch (DCE'd otherwise)

#define RD_ALL(ct) do { \
    _Pragma("unroll") for (int i = 0; i < 2; ++i) { \
        aF[i][0] = *(const bf16x8*)&lds[ct][0][aoff + i * 1024 + ks0]; \
        aF[i][1] = *(const bf16x8*)&lds[ct][0][aoff + i * 1024 + ks1]; } \
    _Pragma("unroll") for (int j = 0; j < 4; ++j) { \
        bF[j][0] = *(const bf16x8*)&lds[ct][1][boff + j * 1024 + ks0]; \
        bF[j][1] = *(const bf16x8*)&lds[ct][1][boff + j * 1024 + ks1]; } \
} while (0)

#define MM8(KS) do { \
    __builtin_amdgcn_s_setprio(1); \
    _Pragma("unroll") for (int i = 0; i < 2; ++i) \
    _Pragma("unroll") for (int j = 0; j < 4; ++j) \
        acc[i][j] = __builtin_amdgcn_mfma_f32_16x16x32_bf16( \
            aF[i][KS], bF[j][KS], acc[i][j], 0, 0, 0); \
    __builtin_amdgcn_s_setprio(0); \
} while (0)

    STG(0, 0);
    STG(1, 1);

#pragma unroll 1
    for (int t = 0; t < NT; ++t) {
        const int c = t & 1;
        if (t < NT - 1) { WAITV(4); } else { WAITV(0); }
        BAR();
        if constexpr (EPI == 4) {
            if (t == NT - 1) {
#pragma unroll
                for (int i = 0; i < 2; ++i)
#pragma unroll
                    for (int r = 0; r < 4; ++r)
#pragma unroll
                        for (int j = 0; j < 4; ++j)
                            xr[i][r][j] = Rb[(size_t)(bm + wm * 32 + i * 16 + koct * 4 + r) * N
                                             + bn + wn * 64 + j * 16 + lrow];
            }
        }
        RD_ALL(c);
        MM8(0);
        asm volatile("s_waitcnt lgkmcnt(0)" ::: "memory");
        __builtin_amdgcn_sched_barrier(0);
        BAR();
        if (t + 2 < NT) STG(c, t + 2);
        MM8(1);
    }

    // epilogue: C/D layout col=lane&15, row=koct*4+reg
    float* Yf = (float*)Y + (size_t)bz * sY;
    __bf16* Yh = (__bf16*)Y + (size_t)bz * sY;
    __bf16* Y6 = (EPI == 6) ? ((bn < 512) ? (__bf16*)Y : (__bf16*)Y2) : nullptr;

    if constexpr (EPI == 7) {
        // write P = exp(min(acc*scale,50)) bf16; reduce block rowsums, no atomics
        float* rsl = (float*)&lds[0][0][0];            // 256 f32 (staging LDS dead)
#pragma unroll
        for (int i = 0; i < 2; ++i)
#pragma unroll
            for (int r = 0; r < 4; ++r) {
                int grow = bm + wm * 32 + i * 16 + koct * 4 + r;
                float ps = 0.f;
#pragma unroll
                for (int j = 0; j < 4; ++j) {
                    float p = __expf(fminf(acc[i][j][r] * scale, 50.f));
                    ps += p;
                    Yh[(size_t)grow * N + bn + wn * 64 + j * 16 + lrow] = (__bf16)p;
                }
                ps += __shfl_xor(ps, 1);
                ps += __shfl_xor(ps, 2);
                ps += __shfl_xor(ps, 4);
                ps += __shfl_xor(ps, 8);
                if (lrow == 0)
                    rsl[wn * 128 + wm * 32 + i * 16 + koct * 4 + r] = ps;
            }
        BAR();
        if (tid < 128) {
            float s2 = rsl[tid] + rsl[128 + tid];
            ((float*)Y2)[((size_t)bz * 1024 + bm + tid) * 8 + (bn >> 7)] = s2;
        }
    } else if constexpr (EPI == 9) {
#pragma unroll
        for (int i = 0; i < 2; ++i)
#pragma unroll
            for (int r = 0; r < 4; ++r) {
                int grow = bm + wm * 32 + i * 16 + koct * 4 + r;
                float rs = resid[(size_t)bz * sR + grow];
#pragma unroll
                for (int j = 0; j < 4; ++j)
                    Yh[(size_t)grow * N + bn + wn * 64 + j * 16 + lrow]
                        = (__bf16)(acc[i][j][r] * rs);
            }
    } else {
#pragma unroll
        for (int i = 0; i < 2; ++i)
#pragma unroll
            for (int r = 0; r < 4; ++r) {
                int grow = bm + wm * 32 + i * 16 + koct * 4 + r;
                float brv = (EPI == 2 || EPI == 4) ? bias[grow] : 0.f;
#pragma unroll
                for (int j = 0; j < 4; ++j) {
                    int gcol = bn + wn * 64 + j * 16 + lrow;
                    float vv = acc[i][j][r];
                    if (EPI == 6) vv += bias[gcol];
                    if (EPI == 2 || EPI == 4) vv += brv;
                    if (EPI == 4) {
                        Yf[(size_t)grow * N + gcol] = vv + xr[i][r][j];
                    } else if (EPI == 6) {
                        Y6[(size_t)grow * 512 + (gcol & 511)] = (__bf16)vv;
                    } else {
                        Yh[(size_t)grow * N + gcol] = (__bf16)vv;
                    }
                }
            }
    }
#undef STG
#undef RD_ALL
#undef MM8
}

extern "C" void kernel_launch(void* const* d_in, const int* in_sizes, int n_in,
                              void* d_out, int out_size, void* d_ws, size_t ws_size,
                              hipStream_t stream) {
    const float* x      = (const float*)d_in[0];
    const float* norm_w = (const float*)d_in[1];
    const float* norm_b = (const float*)d_in[2];
    const float* q_w    = (const float*)d_in[3];
    const float* q_b    = (const float*)d_in[4];
    const float* k_w    = (const float*)d_in[5];
    const float* k_b    = (const float*)d_in[6];
    const float* v_w    = (const float*)d_in[7];
    const float* v_b    = (const float*)d_in[8];
    const float* proj_w = (const float*)d_in[9];
    const float* proj_b = (const float*)d_in[10];
    float* out = (float*)d_out;

    const size_t ELEM = (size_t)N_SP * C_DIM;            // 524288 elems = 1MB bf16
    const size_t QK   = (size_t)N_SP * N_SP;
    char* ws = (char*)d_ws;
    __bf16* hT  = (__bf16*)ws;                           // 32MB [b][n][c], reused as Ot
    __bf16* qT  = (__bf16*)(ws + ((size_t)32 << 20));    // 32MB [b][n][512]
    __bf16* kT  = (__bf16*)(ws + ((size_t)64 << 20));    // 32MB [b][n][512]
    __bf16* wqk = (__bf16*)(ws + ((size_t)96 << 20));    // 1MB [1024][512]
    __bf16* wv  = (__bf16*)(ws + ((size_t)97 << 20));    // 0.5MB
    __bf16* wp  = wv + 262144;                           // 0.5MB
    float* qkb  = (float*)(ws + ((size_t)98 << 20));     // 4KB
    float* RS   = (float*)(ws + ((size_t)98 << 20) + (64 << 10));    // 128KB: 1/rowsum
    float* RSp  = (float*)(ws + ((size_t)98 << 20) + (192 << 10));   // 1MB: partials [b][row][8]
    size_t sbase = ((size_t)99 << 20) + (256 << 10);
    __bf16* S = (__bf16*)(ws + sbase);                   // chunk x [1024][1024] bf16
    __bf16* v  = (__bf16*)d_out;                         // V lives in d_out until proj
    __bf16* Ot = hT;

    int chunk = (int)((ws_size - sbase) >> 21);          // 2MB per batch of S
    if (chunk > B_DIM) chunk = B_DIM;
    if (chunk < 1) chunk = 1;

    gn_fused_kernel<<<B_DIM * GROUPS, 256, 0, stream>>>(x, norm_w, norm_b, hT);
    prep_kernel<<<1025, 256, 0, stream>>>(q_w, k_w, v_w, proj_w, q_b, k_b,
                                          wqk, wv, wp, qkb);

    // qT[n][oc] / kT[n][oc] = hT[n][:] x (wq||wk)^T + bias, split outputs
    gemmP<32768, 1024, 512, 512, 512, 6><<<2048, 512, 0, stream>>>(
        hT, 0, wqk, 0, qT, 0, qkb, nullptr, 0, 1.f, kT);
    // v[b][oc][n] = wv[oc][:] x hT[b][n][:] + v_b[oc]
    gemmP<512, 1024, 512, 512, 512, 2><<<1024, 512, 0, stream>>>(
        wv, 0, hT, ELEM, v, ELEM, v_b, nullptr, 0, 1.f, nullptr);

    const float scale = 0.044194173824159216f;  // 512^-0.5
    for (int b0 = 0; b0 < B_DIM; b0 += chunk) {
        int nb = (b0 + chunk <= B_DIM) ? chunk : (B_DIM - b0);
        // S[i][j] = exp(scale * q.k) bf16 (unnormalized) + rowsum partials
        gemmP<1024, 1024, 512, 512, 512, 7><<<64 * nb, 512, 0, stream>>>(
            qT + (size_t)b0 * ELEM, ELEM, kT + (size_t)b0 * ELEM, ELEM,
            S, QK, nullptr, nullptr, 0, scale, RSp + (size_t)b0 * 8192);
        // RS = 1 / sum(partials)
        rs_fold<<<nb * 4, 256, 0, stream>>>(RSp + (size_t)b0 * 8192,
                                            RS + (size_t)b0 * 1024);
        // Ot[i][c] = (sum_j P[i][j] v[c][j]) * RS[i]
        gemmP<1024, 512, 1024, 1024, 1024, 9><<<32 * nb, 512, 0, stream>>>(
            S, QK, v + (size_t)b0 * ELEM, ELEM,
            Ot + (size_t)b0 * ELEM, ELEM, nullptr,
            RS + (size_t)b0 * 1024, 1024, 1.f, nullptr);
    }

    // out[b][oc][n] = wp[oc][:] x Ot[b][n][:] + proj_b[oc] + x[b][oc][n]
    gemmP<512, 1024, 512, 512, 512, 4><<<1024, 512, 0, stream>>>(
        wp, 0, Ot, ELEM, out, ELEM, proj_b, x, ELEM, 1.f, nullptr);
}